// Round 1
// baseline (159.539 us; speedup 1.0000x reference)
//
#include <hip/hip_runtime.h>
#include <hip/hip_bf16.h>

#define J_JOINTS 17
#define BLOCK 256
#define ROWS_PER_BLOCK 16   // BLOCK / 16 lanes-per-row
#define GRID 2048

__global__ __launch_bounds__(BLOCK) void loss_main_kernel(
    const float* __restrict__ outp,   // (B, 17, 3)
    const float* __restrict__ tgt,    // (B, 17, 3)
    double* __restrict__ acc,         // acc[0]=cls_sum, acc[1]=reg_sum
    int B)
{
    const int tid = threadIdx.x;
    const int seg = tid >> 4;    // which row within this block's group of 16
    const int pos = tid & 15;    // joint index 0..15 (pos 0 also handles j=16)

    float cls_acc = 0.0f;   // sum of class-loss terms handled by this thread
    float reg_acc = 0.0f;   // sum of per-row reg-loss terms (only pos==0 adds)

    const long long rowsPerIter = (long long)gridDim.x * ROWS_PER_BLOCK;
    const long long numIter = ((long long)B + rowsPerIter - 1) / rowsPerIter;

    for (long long it = 0; it < numIter; ++it) {
        const long long b = it * rowsPerIter + (long long)blockIdx.x * ROWS_PER_BLOCK + seg;

        float sq = 0.0f;   // keep-masked squared diff for this (b, pos[, 16])
        float nj = 0.0f;   // joint count contribution

        if (b < B) {
            // element index fits in 32 bits: b*51 + pos*3 <= 51e6
            const int base = (int)b * (J_JOINTS * 3) + pos * 3;
            const float o0 = outp[base + 0];
            const float o1 = outp[base + 1];
            const float p  = outp[base + 2];
            const float t0 = tgt[base + 0];
            const float t1 = tgt[base + 1];
            const float cg = tgt[base + 2];

            const float lp   = fmaxf(logf(p),      -100.0f);
            const float l1mp = fmaxf(log1pf(-p),   -100.0f);
            cls_acc += cg * lp + (1.0f - cg) * l1mp;

            const bool keep = (p >= 0.5f);
            const float d0 = keep ? (o0 - t0) : 0.0f;
            const float d1 = keep ? (o1 - t1) : 0.0f;
            sq = d0 * d0 + d1 * d1;
            nj = (cg == 1.0f) ? 1.0f : 0.0f;

            if (pos == 0) {
                // joint 16 for this row
                const int base16 = (int)b * (J_JOINTS * 3) + 16 * 3;
                const float o0b = outp[base16 + 0];
                const float o1b = outp[base16 + 1];
                const float pb  = outp[base16 + 2];
                const float t0b = tgt[base16 + 0];
                const float t1b = tgt[base16 + 1];
                const float cgb = tgt[base16 + 2];

                const float lpb   = fmaxf(logf(pb),    -100.0f);
                const float l1mpb = fmaxf(log1pf(-pb), -100.0f);
                cls_acc += cgb * lpb + (1.0f - cgb) * l1mpb;

                const bool keepb = (pb >= 0.5f);
                const float d0b = keepb ? (o0b - t0b) : 0.0f;
                const float d1b = keepb ? (o1b - t1b) : 0.0f;
                sq += d0b * d0b + d1b * d1b;
                nj += (cgb == 1.0f) ? 1.0f : 0.0f;
            }
        }

        // segmented reduce across the 16-lane group (xor masks stay in-group)
        #pragma unroll
        for (int m = 1; m < 16; m <<= 1) {
            sq += __shfl_xor(sq, m, 64);
            nj += __shfl_xor(nj, m, 64);
        }

        if (pos == 0 && b < B) {
            reg_acc += 0.5f * sq / (1.0f + nj);
        }
    }

    // ---- block reduction ----
    // wave-level
    #pragma unroll
    for (int m = 1; m < 64; m <<= 1) {
        cls_acc += __shfl_xor(cls_acc, m, 64);
        reg_acc += __shfl_xor(reg_acc, m, 64);
    }
    __shared__ float s_cls[BLOCK / 64];
    __shared__ float s_reg[BLOCK / 64];
    const int wid = tid >> 6;
    if ((tid & 63) == 0) {
        s_cls[wid] = cls_acc;
        s_reg[wid] = reg_acc;
    }
    __syncthreads();
    if (tid == 0) {
        float c = 0.0f, r = 0.0f;
        #pragma unroll
        for (int w = 0; w < BLOCK / 64; ++w) { c += s_cls[w]; r += s_reg[w]; }
        atomicAdd(&acc[0], (double)c);
        atomicAdd(&acc[1], (double)r);
    }
}

__global__ void loss_finalize_kernel(const double* __restrict__ acc,
                                     float* __restrict__ out, int B)
{
    const double cls_sum = acc[0];
    const double reg_sum = acc[1];
    const double loss_class = -cls_sum / ((double)B * (double)J_JOINTS);
    const double loss_reg   = reg_sum / (double)B;
    out[0] = (float)(loss_class + loss_reg);
}

extern "C" void kernel_launch(void* const* d_in, const int* in_sizes, int n_in,
                              void* d_out, int out_size, void* d_ws, size_t ws_size,
                              hipStream_t stream) {
    const float* outp = (const float*)d_in[0];
    const float* tgt  = (const float*)d_in[1];
    float* out = (float*)d_out;
    const int B = in_sizes[0] / (J_JOINTS * 3);

    double* acc = (double*)d_ws;
    hipMemsetAsync(acc, 0, 2 * sizeof(double), stream);

    loss_main_kernel<<<GRID, BLOCK, 0, stream>>>(outp, tgt, acc, B);
    loss_finalize_kernel<<<1, 1, 0, stream>>>(acc, out, B);
}

// Round 2
// 126.818 us; speedup vs baseline: 1.2580x; 1.2580x over previous
//
#include <hip/hip_runtime.h>
#include <hip/hip_bf16.h>

#define J_JOINTS 17
#define BLOCK 256
#define ROWS_PER_BLOCK 16   // BLOCK / 16 lanes-per-row
#define GRID 2048

struct __align__(4) F3 { float x, y, z; };

__global__ __launch_bounds__(BLOCK) void loss_main_kernel(
    const float* __restrict__ outp,   // (B, 17, 3)
    const float* __restrict__ tgt,    // (B, 17, 3)
    double* __restrict__ acc,         // acc[0]=cls_sum, acc[1]=reg_sum
    int B)
{
    const int tid   = threadIdx.x;
    const int seg   = tid >> 4;          // row slot within block (0..15)
    const int pos   = tid & 15;          // joint 0..15 (pos 0 also does j=16)
    const int grp16 = (tid & 63) >> 4;   // 16-lane group within the wave

    float cls_acc = 0.0f;
    float reg_acc = 0.0f;

    const int rowsPerIter = GRID * ROWS_PER_BLOCK;            // 32768
    const int numIter = (B + rowsPerIter - 1) / rowsPerIter;  // uniform count
    const int b0 = blockIdx.x * ROWS_PER_BLOCK + seg;

    for (int it = 0; it < numIter; ++it) {
        const int b = it * rowsPerIter + b0;

        float sq   = 0.0f;   // keep-masked squared diff for this joint (+j16 at pos0)
        float nj16 = 0.0f;   // joint-16 count contribution (pos0 only)
        bool  gt1  = false;  // class_gt == 1 for this lane's joint

        if (b < B) {
            const int base = b * (J_JOINTS * 3) + pos * 3;
            const F3 o = *reinterpret_cast<const F3*>(outp + base);
            const F3 t = *reinterpret_cast<const F3*>(tgt  + base);

            gt1 = (t.z == 1.0f);
            // only one log needed since class_gt is exactly 0 or 1
            const float x = gt1 ? o.z : (1.0f - o.z);
            cls_acc += fmaxf(__logf(x), -100.0f);

            const bool keep = (o.z >= 0.5f);
            const float d0 = keep ? (o.x - t.x) : 0.0f;
            const float d1 = keep ? (o.y - t.y) : 0.0f;
            sq = fmaf(d0, d0, d1 * d1);

            if (pos == 0) {
                const int base16 = b * (J_JOINTS * 3) + 16 * 3;
                const F3 ob = *reinterpret_cast<const F3*>(outp + base16);
                const F3 tb = *reinterpret_cast<const F3*>(tgt  + base16);

                const bool gt1b = (tb.z == 1.0f);
                const float xb = gt1b ? ob.z : (1.0f - ob.z);
                cls_acc += fmaxf(__logf(xb), -100.0f);

                const bool keepb = (ob.z >= 0.5f);
                const float d0b = keepb ? (ob.x - tb.x) : 0.0f;
                const float d1b = keepb ? (ob.y - tb.y) : 0.0f;
                sq += fmaf(d0b, d0b, d1b * d1b);
                nj16 = gt1b ? 1.0f : 0.0f;
            }
        }

        // num_joints for the 16 lane-joints via ballot (uniform control flow here)
        const unsigned long long bal = __ballot(gt1);

        // segmented sum of sq across the 16-lane group
        #pragma unroll
        for (int m = 1; m < 16; m <<= 1) {
            sq += __shfl_xor(sq, m, 64);
        }

        if (pos == 0 && b < B) {
            const float njoints =
                1.0f + nj16 +
                (float)__popcll((bal >> (grp16 * 16)) & 0xFFFFull);
            reg_acc += __fdividef(0.5f * sq, njoints);
        }
    }

    // ---- block reduction ----
    #pragma unroll
    for (int m = 1; m < 64; m <<= 1) {
        cls_acc += __shfl_xor(cls_acc, m, 64);
        reg_acc += __shfl_xor(reg_acc, m, 64);
    }
    __shared__ float s_cls[BLOCK / 64];
    __shared__ float s_reg[BLOCK / 64];
    const int wid = tid >> 6;
    if ((tid & 63) == 0) {
        s_cls[wid] = cls_acc;
        s_reg[wid] = reg_acc;
    }
    __syncthreads();
    if (tid == 0) {
        float c = 0.0f, r = 0.0f;
        #pragma unroll
        for (int w = 0; w < BLOCK / 64; ++w) { c += s_cls[w]; r += s_reg[w]; }
        atomicAdd(&acc[0], (double)c);
        atomicAdd(&acc[1], (double)r);
    }
}

__global__ void loss_finalize_kernel(const double* __restrict__ acc,
                                     float* __restrict__ out, int B)
{
    const double cls_sum = acc[0];
    const double reg_sum = acc[1];
    const double loss_class = -cls_sum / ((double)B * (double)J_JOINTS);
    const double loss_reg   = reg_sum / (double)B;
    out[0] = (float)(loss_class + loss_reg);
}

extern "C" void kernel_launch(void* const* d_in, const int* in_sizes, int n_in,
                              void* d_out, int out_size, void* d_ws, size_t ws_size,
                              hipStream_t stream) {
    const float* outp = (const float*)d_in[0];
    const float* tgt  = (const float*)d_in[1];
    float* out = (float*)d_out;
    const int B = in_sizes[0] / (J_JOINTS * 3);

    double* acc = (double*)d_ws;
    hipMemsetAsync(acc, 0, 2 * sizeof(double), stream);

    loss_main_kernel<<<GRID, BLOCK, 0, stream>>>(outp, tgt, acc, B);
    loss_finalize_kernel<<<1, 1, 0, stream>>>(acc, out, B);
}

// Round 3
// 97.198 us; speedup vs baseline: 1.6414x; 1.3047x over previous
//
#include <hip/hip_runtime.h>
#include <hip/hip_bf16.h>

#define J_JOINTS 17
#define ROW_F 51                       // floats per row per array (17*3)
#define BLOCK 256
#define TILE_ROWS 128                  // rows per tile; 2 threads per row
#define TILE_F (TILE_ROWS * ROW_F)     // 6528 floats per array per tile
#define GRID 768                       // 3 blocks/CU (LDS-limited), 256 CUs

__global__ __launch_bounds__(BLOCK) void loss_main_kernel(
    const float* __restrict__ outp,   // (B, 17, 3)
    const float* __restrict__ tgt,    // (B, 17, 3)
    double* __restrict__ acc,         // acc[0]=cls_sum, acc[1]=reg_sum
    int B)
{
    __shared__ float so[TILE_F];      // 26112 B
    __shared__ float st[TILE_F];      // 26112 B  (52224 B total -> 3 blocks/CU)

    const int tid  = threadIdx.x;
    const int r2   = tid >> 1;        // local row handled by this thread pair
    const int half = tid & 1;         // 0: joints 0..7, 1: joints 8..16

    float cls_acc = 0.0f;
    float reg_acc = 0.0f;

    const int stride_rows = (int)gridDim.x * TILE_ROWS;   // 98304

    for (int row0 = (int)blockIdx.x * TILE_ROWS; row0 < B; row0 += stride_rows) {
        const int rows_valid = min(TILE_ROWS, B - row0);
        const int nv = rows_valid * ROW_F;      // valid floats this tile
        const int n4 = nv >> 2;                 // full float4 count

        // ---- stage: fully-coalesced float4 global -> LDS (linear) ----
        const float4* src_o = reinterpret_cast<const float4*>(outp + row0 * ROW_F);
        const float4* src_t = reinterpret_cast<const float4*>(tgt  + row0 * ROW_F);
        float4* dst_o = reinterpret_cast<float4*>(so);
        float4* dst_t = reinterpret_cast<float4*>(st);
        for (int i = tid; i < n4; i += BLOCK) {
            dst_o[i] = src_o[i];
            dst_t[i] = src_t[i];
        }
        const int tb = n4 << 2;                 // scalar tail (0..3 elems)
        if (tid < (nv - tb)) {
            so[tb + tid] = outp[row0 * ROW_F + tb + tid];
            st[tb + tid] = tgt [row0 * ROW_F + tb + tid];
        }
        __syncthreads();

        // ---- compute: one row per thread pair, all reads from LDS ----
        float sq = 0.0f;
        float nj = 0.0f;
        if (r2 < rows_valid) {
            const int base = r2 * ROW_F + half * 24;   // joints 0..7 or 8..15
            #pragma unroll
            for (int k = 0; k < 8; ++k) {
                const float ox = so[base + 3*k + 0];
                const float oy = so[base + 3*k + 1];
                const float oz = so[base + 3*k + 2];
                const float tx = st[base + 3*k + 0];
                const float ty = st[base + 3*k + 1];
                const float tz = st[base + 3*k + 2];

                const bool gt1 = (tz == 1.0f);
                cls_acc += fmaxf(__logf(gt1 ? oz : (1.0f - oz)), -100.0f);

                const bool keep = (oz >= 0.5f);
                const float d0 = keep ? (ox - tx) : 0.0f;
                const float d1 = keep ? (oy - ty) : 0.0f;
                sq = fmaf(d0, d0, fmaf(d1, d1, sq));
                nj += gt1 ? 1.0f : 0.0f;
            }
            if (half) {   // joint 16
                const int b16 = r2 * ROW_F + 48;
                const float ox = so[b16 + 0];
                const float oy = so[b16 + 1];
                const float oz = so[b16 + 2];
                const float tx = st[b16 + 0];
                const float ty = st[b16 + 1];
                const float tz = st[b16 + 2];

                const bool gt1 = (tz == 1.0f);
                cls_acc += fmaxf(__logf(gt1 ? oz : (1.0f - oz)), -100.0f);

                const bool keep = (oz >= 0.5f);
                const float d0 = keep ? (ox - tx) : 0.0f;
                const float d1 = keep ? (oy - ty) : 0.0f;
                sq = fmaf(d0, d0, fmaf(d1, d1, sq));
                nj += gt1 ? 1.0f : 0.0f;
            }
        }

        // pair-combine (lanes 2k <-> 2k+1): the ONLY cross-lane work per row
        sq += __shfl_xor(sq, 1, 64);
        nj += __shfl_xor(nj, 1, 64);
        if (!half && r2 < rows_valid) {
            reg_acc += __fdividef(0.5f * sq, 1.0f + nj);
        }
        __syncthreads();   // protect LDS before next tile's stage
    }

    // ---- block reduction ----
    #pragma unroll
    for (int m = 1; m < 64; m <<= 1) {
        cls_acc += __shfl_xor(cls_acc, m, 64);
        reg_acc += __shfl_xor(reg_acc, m, 64);
    }
    __shared__ float s_cls[BLOCK / 64];
    __shared__ float s_reg[BLOCK / 64];
    const int wid = tid >> 6;
    if ((tid & 63) == 0) {
        s_cls[wid] = cls_acc;
        s_reg[wid] = reg_acc;
    }
    __syncthreads();
    if (tid == 0) {
        float c = 0.0f, r = 0.0f;
        #pragma unroll
        for (int w = 0; w < BLOCK / 64; ++w) { c += s_cls[w]; r += s_reg[w]; }
        atomicAdd(&acc[0], (double)c);
        atomicAdd(&acc[1], (double)r);
    }
}

__global__ void loss_finalize_kernel(const double* __restrict__ acc,
                                     float* __restrict__ out, int B)
{
    const double cls_sum = acc[0];
    const double reg_sum = acc[1];
    const double loss_class = -cls_sum / ((double)B * (double)J_JOINTS);
    const double loss_reg   = reg_sum / (double)B;
    out[0] = (float)(loss_class + loss_reg);
}

extern "C" void kernel_launch(void* const* d_in, const int* in_sizes, int n_in,
                              void* d_out, int out_size, void* d_ws, size_t ws_size,
                              hipStream_t stream) {
    const float* outp = (const float*)d_in[0];
    const float* tgt  = (const float*)d_in[1];
    float* out = (float*)d_out;
    const int B = in_sizes[0] / (J_JOINTS * 3);

    double* acc = (double*)d_ws;
    hipMemsetAsync(acc, 0, 2 * sizeof(double), stream);

    loss_main_kernel<<<GRID, BLOCK, 0, stream>>>(outp, tgt, acc, B);
    loss_finalize_kernel<<<1, 1, 0, stream>>>(acc, out, B);
}

// Round 4
// 87.492 us; speedup vs baseline: 1.8235x; 1.1109x over previous
//
#include <hip/hip_runtime.h>
#include <hip/hip_bf16.h>
#include <stdint.h>

#define J_JOINTS 17
#define ROW_F 51                         // floats per row per array
#define BLOCK 256
#define TILE_ROWS 64                     // rows per tile buffer; 4 threads/row
#define TILE_F (TILE_ROWS * ROW_F)       // 3264 floats per array per buffer
#define TILE_CHUNKS (TILE_F / 4)         // 816 16B chunks per array per buffer
#define GRID 768                         // 3 blocks/CU (52 KB LDS each)

__device__ __forceinline__ void gld_lds16(const float* g, float* l) {
    // async global -> LDS, 16B per lane; LDS dest = wave base + lane*16
    __builtin_amdgcn_global_load_lds(
        (const __attribute__((address_space(1))) void*)g,
        (__attribute__((address_space(3))) void*)l,
        16, 0, 0);
}

__global__ __launch_bounds__(BLOCK) void loss_main_kernel(
    const float* __restrict__ outp,   // (B, 17, 3)
    const float* __restrict__ tgt,    // (B, 17, 3)
    double* __restrict__ acc,         // acc[0]=cls_sum, acc[1]=reg_sum
    int B)
{
    __shared__ float so[2][TILE_F];
    __shared__ float st[2][TILE_F];

    const int tid = threadIdx.x;
    const int r4  = tid >> 2;   // local row (0..63)
    const int q   = tid & 3;    // joint quarter: joints 4q..4q+3 (+16 if q==3)

    float cls_acc = 0.0f;
    float reg_acc = 0.0f;

    const int tiles_total = (B + TILE_ROWS - 1) / TILE_ROWS;

    // ---- stage helpers (inlined logic) ----
    // fast path: full tile, async direct-to-LDS
    auto stage_async = [&](int row0, int buf) {
        const float* go = outp + row0 * ROW_F;
        const float* gt = tgt  + row0 * ROW_F;
        float* lo = so[buf];
        float* lt = st[buf];
        #pragma unroll
        for (int j = 0; j < 4; ++j) {
            const int i = tid + j * BLOCK;
            if (i < TILE_CHUNKS) {
                gld_lds16(go + i * 4, lo + i * 4);
                gld_lds16(gt + i * 4, lt + i * 4);
            }
        }
    };
    // slow path: partial tile, guarded sync loads (only if B % TILE_ROWS != 0)
    auto stage_sync = [&](int row0, int rows_valid, int buf) {
        const float* go = outp + row0 * ROW_F;
        const float* gt = tgt  + row0 * ROW_F;
        const int nv = rows_valid * ROW_F;
        const int n4 = nv >> 2;
        for (int i = tid; i < n4; i += BLOCK) {
            reinterpret_cast<float4*>(so[buf])[i] = reinterpret_cast<const float4*>(go)[i];
            reinterpret_cast<float4*>(st[buf])[i] = reinterpret_cast<const float4*>(gt)[i];
        }
        const int tb = n4 << 2;
        if (tid < nv - tb) {
            so[buf][tb + tid] = go[tb + tid];
            st[buf][tb + tid] = gt[tb + tid];
        }
    };
    auto stage = [&](int tk, int buf) {
        const int row0 = tk * TILE_ROWS;
        if (row0 + TILE_ROWS <= B) stage_async(row0, buf);
        else                       stage_sync(row0, B - row0, buf);
    };

    // ---- pipeline ----
    int tk  = blockIdx.x;
    int cur = 0;

    if (tk < tiles_total) stage(tk, 0);
    asm volatile("s_waitcnt vmcnt(0)" ::: "memory");
    __syncthreads();

    while (tk < tiles_total) {
        const int tn = tk + GRID;
        if (tn < tiles_total) stage(tn, cur ^ 1);   // async issue: in flight during compute

        // ---- compute buf[cur] from LDS ----
        const int rows_valid = min(TILE_ROWS, B - tk * TILE_ROWS);
        float sq = 0.0f;
        float nj = 0.0f;
        if (r4 < rows_valid) {
            const float* lo = so[cur] + r4 * ROW_F + q * 12;
            const float* lt = st[cur] + r4 * ROW_F + q * 12;
            #pragma unroll
            for (int k = 0; k < 4; ++k) {
                const float ox = lo[3*k + 0];
                const float oy = lo[3*k + 1];
                const float oz = lo[3*k + 2];
                const float tx = lt[3*k + 0];
                const float ty = lt[3*k + 1];
                const float tz = lt[3*k + 2];

                const bool gt1 = (tz == 1.0f);
                cls_acc += fmaxf(__logf(gt1 ? oz : (1.0f - oz)), -100.0f);

                const bool keep = (oz >= 0.5f);
                const float d0 = keep ? (ox - tx) : 0.0f;
                const float d1 = keep ? (oy - ty) : 0.0f;
                sq = fmaf(d0, d0, fmaf(d1, d1, sq));
                nj += gt1 ? 1.0f : 0.0f;
            }
            if (q == 3) {   // joint 16 (offset 48 floats from row start = 12 past q*12)
                const float ox = lo[12 + 0];
                const float oy = lo[12 + 1];
                const float oz = lo[12 + 2];
                const float tx = lt[12 + 0];
                const float ty = lt[12 + 1];
                const float tz = lt[12 + 2];

                const bool gt1 = (tz == 1.0f);
                cls_acc += fmaxf(__logf(gt1 ? oz : (1.0f - oz)), -100.0f);

                const bool keep = (oz >= 0.5f);
                const float d0 = keep ? (ox - tx) : 0.0f;
                const float d1 = keep ? (oy - ty) : 0.0f;
                sq = fmaf(d0, d0, fmaf(d1, d1, sq));
                nj += gt1 ? 1.0f : 0.0f;
            }
        }
        // segmented reduce across the 4-lane row group
        sq += __shfl_xor(sq, 1, 64);  nj += __shfl_xor(nj, 1, 64);
        sq += __shfl_xor(sq, 2, 64);  nj += __shfl_xor(nj, 2, 64);
        if (q == 0 && r4 < rows_valid) {
            reg_acc += __fdividef(0.5f * sq, 1.0f + nj);
        }

        // drain next-tile loads + protect LDS buffers
        asm volatile("s_waitcnt vmcnt(0)" ::: "memory");
        __syncthreads();
        cur ^= 1;
        tk = tn;
    }

    // ---- block reduction ----
    #pragma unroll
    for (int m = 1; m < 64; m <<= 1) {
        cls_acc += __shfl_xor(cls_acc, m, 64);
        reg_acc += __shfl_xor(reg_acc, m, 64);
    }
    __shared__ float s_cls[BLOCK / 64];
    __shared__ float s_reg[BLOCK / 64];
    const int wid = tid >> 6;
    if ((tid & 63) == 0) {
        s_cls[wid] = cls_acc;
        s_reg[wid] = reg_acc;
    }
    __syncthreads();
    if (tid == 0) {
        float c = 0.0f, r = 0.0f;
        #pragma unroll
        for (int w = 0; w < BLOCK / 64; ++w) { c += s_cls[w]; r += s_reg[w]; }
        atomicAdd(&acc[0], (double)c);
        atomicAdd(&acc[1], (double)r);
    }
}

__global__ void loss_finalize_kernel(const double* __restrict__ acc,
                                     float* __restrict__ out, int B)
{
    const double cls_sum = acc[0];
    const double reg_sum = acc[1];
    const double loss_class = -cls_sum / ((double)B * (double)J_JOINTS);
    const double loss_reg   = reg_sum / (double)B;
    out[0] = (float)(loss_class + loss_reg);
}

extern "C" void kernel_launch(void* const* d_in, const int* in_sizes, int n_in,
                              void* d_out, int out_size, void* d_ws, size_t ws_size,
                              hipStream_t stream) {
    const float* outp = (const float*)d_in[0];
    const float* tgt  = (const float*)d_in[1];
    float* out = (float*)d_out;
    const int B = in_sizes[0] / (J_JOINTS * 3);

    double* acc = (double*)d_ws;
    hipMemsetAsync(acc, 0, 2 * sizeof(double), stream);

    loss_main_kernel<<<GRID, BLOCK, 0, stream>>>(outp, tgt, acc, B);
    loss_finalize_kernel<<<1, 1, 0, stream>>>(acc, out, B);
}